// Round 12
// baseline (228.241 us; speedup 1.0000x reference)
//
#include <hip/hip_runtime.h>
#include <hip/hip_bf16.h>

// Problem constants
#define N_NODES 16384
#define C_DIM   128
#define E_EDGES 262144
#define S_SPEC  10
#define CHUNK   256
#define PROWS   16544   // N + 10*15 rounded to 16: padded species-sorted rows
#define PTILES  1034    // PROWS / 16

__device__ __constant__ const float INV_C  = 0.08838834764831845f;  // 1/sqrt(128)
__device__ __constant__ const float INV_2C = 0.0625f;               // 1/sqrt(256)
#define F_INV_SQRT3 0.5773502691896258f
#define F_INV_SQRT8 0.35355339059327373f
#define F_INV_AVG   0.0625f   // 1/16 neighbors

typedef __attribute__((ext_vector_type(8))) short bf16x8;
typedef __attribute__((ext_vector_type(4))) float f32x4;

__device__ __forceinline__ float silu(float x) {
    return x / (1.0f + __expf(-x));
}

__device__ __forceinline__ unsigned short f2bf(float x) {
    __hip_bfloat16 h = __float2bfloat16(x);
    return *reinterpret_cast<unsigned short*>(&h);
}

__device__ __forceinline__ unsigned int pack2bf(float lo, float hi) {
    return (unsigned int)f2bf(lo) | ((unsigned int)f2bf(hi) << 16);
}

__device__ __forceinline__ float bf2f(unsigned int u16) {
    return __uint_as_float((u16 & 0xffffu) << 16);
}

__device__ __forceinline__ float bf2f_hi(unsigned int u) {
    return __uint_as_float(u & 0xffff0000u);
}

// ---------------------------------------------------------------------------
// Init: replaces 4 memsets with one dispatch.
// ---------------------------------------------------------------------------
__global__ __launch_bounds__(256) void init_kernel(
    int* __restrict__ counts, int* __restrict__ scnt,
    int* __restrict__ prow_map, int* __restrict__ tile_spec)
{
    const int idx = blockIdx.x * 256 + threadIdx.x;
    if (idx < N_NODES) counts[idx] = 0;
    if (idx < S_SPEC)  scnt[idx] = 0;
    if (idx < PROWS)   prow_map[idx] = -1;
    if (idx < PTILES)  tile_spec[idx] = 0;
}

// ---------------------------------------------------------------------------
// Histograms: receiver degree (all blocks) + species (first 64 blocks).
// ---------------------------------------------------------------------------
__global__ __launch_bounds__(256) void hist_kernel(
    const int* __restrict__ receivers, int* __restrict__ cnt,
    const int* __restrict__ specie, int* __restrict__ scnt)
{
    __shared__ int h[S_SPEC];
    const int t = threadIdx.x;
    const bool doSpec = blockIdx.x < (N_NODES / 256);
    if (doSpec) {
        if (t < S_SPEC) h[t] = 0;
        __syncthreads();
        atomicAdd(&h[specie[blockIdx.x * 256 + t]], 1);
    }
    const int e = blockIdx.x * 256 + t;
    atomicAdd(&cnt[receivers[e]], 1);
    if (doSpec) {
        __syncthreads();
        if (t < S_SPEC) atomicAdd(&scnt[t], h[t]);
    }
}

// ---------------------------------------------------------------------------
// Scans: 16K-node CSR scan (+cursor copy) and 10-species padded scan.
// ---------------------------------------------------------------------------
__global__ __launch_bounds__(256) void scan_kernel(
    const int* __restrict__ cnt, int* __restrict__ start,
    int* __restrict__ cursor,
    const int* __restrict__ scnt, int* __restrict__ poff,
    int* __restrict__ scur)
{
    __shared__ int sums[256];
    const int t = threadIdx.x;
    if (t == 0) {
        int pa = 0;
        for (int i = 0; i < S_SPEC; ++i) {
            poff[i] = pa;
            scur[i] = 0;
            pa += ((scnt[i] + 15) >> 4) << 4;
        }
    }
    int s = 0;
    for (int i = 0; i < 64; ++i) s += cnt[t * 64 + i];
    sums[t] = s;
    __syncthreads();
    if (t == 0) {
        int a = 0;
        for (int i = 0; i < 256; ++i) { int v = sums[i]; sums[i] = a; a += v; }
    }
    __syncthreads();
    int a = sums[t];
    for (int i = 0; i < 64; ++i) {
        int v = cnt[t * 64 + i];
        start[t * 64 + i] = a;
        cursor[t * 64 + i] = a;
        a += v;
    }
    if (t == 255) start[N_NODES] = a;
}

// ---------------------------------------------------------------------------
// Scatter: CSR edge permutation (all blocks) + node placement (first 64).
// ---------------------------------------------------------------------------
__global__ __launch_bounds__(256) void scatter_place_kernel(
    const int* __restrict__ receivers, int* __restrict__ cursor,
    int* __restrict__ perm,
    const int* __restrict__ specie, const int* __restrict__ poff,
    int* __restrict__ scur,
    int* __restrict__ prow_map, int* __restrict__ tile_spec)
{
    const int t = threadIdx.x;
    const int e = blockIdx.x * 256 + t;
    const int pos = atomicAdd(&cursor[receivers[e]], 1);
    perm[pos] = e;

    if (blockIdx.x < (N_NODES / 256)) {
        __shared__ int h[S_SPEC];
        __shared__ int bbase[S_SPEC];
        if (t < S_SPEC) h[t] = 0;
        __syncthreads();
        const int n = blockIdx.x * 256 + t;
        const int s = specie[n];
        const int lrank = atomicAdd(&h[s], 1);
        __syncthreads();
        if (t < S_SPEC && h[t] > 0) bbase[t] = atomicAdd(&scur[t], h[t]);
        __syncthreads();
        const int p = poff[s] + bbase[s] + lrank;
        prow_map[p] = n;
        tile_spec[p >> 4] = s;    // benign race: same value within a tile
    }
}

// ---------------------------------------------------------------------------
// Prep: all bf16 conversions in one dispatch (streaming, range-switched).
// ---------------------------------------------------------------------------
__global__ __launch_bounds__(256) void prep_kernel(
    const int* __restrict__ prow_map, const float* __restrict__ node_feats,
    ushort* __restrict__ As, ushort* __restrict__ Av0,
    ushort* __restrict__ Av1, ushort* __restrict__ Av2,
    const float* __restrict__ Wsc0, const float* __restrict__ Wsc1,
    ushort* __restrict__ Wsc0t, ushort* __restrict__ Wsc1t,
    const float* __restrict__ Wpre0, const float* __restrict__ Wpre1,
    ushort* __restrict__ Wpre0t, ushort* __restrict__ Wpre1t,
    const float* __restrict__ Wp0, const float* __restrict__ Wp1,
    ushort* __restrict__ Bt0, ushort* __restrict__ Bt1,
    const float* __restrict__ Wm1, const float* __restrict__ Wm2,
    const float* __restrict__ Wm3,
    ushort* __restrict__ W1t, ushort* __restrict__ W2t,
    ushort* __restrict__ W3t)
{
    const int idx = blockIdx.x * 256 + threadIdx.x;   // 0 .. PROWS*128-1
    {
        const int p = idx >> 7, c = idx & 127;
        const int nid = prow_map[p];
        float4 f = {0.0f, 0.0f, 0.0f, 0.0f};
        if (nid >= 0) f = ((const float4*)node_feats)[nid * C_DIM + c];
        As [idx] = f2bf(f.x);
        Av0[idx] = f2bf(f.y);
        Av1[idx] = f2bf(f.z);
        Av2[idx] = f2bf(f.w);
    }
    if (idx < S_SPEC * 128 * 128) {
        const int s = idx >> 14, d = (idx >> 7) & 127, k = idx & 127;
        Wsc0t[idx] = f2bf(Wsc0[s * 16384 + k * 128 + d] * INV_C);
        Wsc1t[idx] = f2bf(Wsc1[s * 16384 + k * 128 + d] * INV_C);
    }
    if (idx < 16384) {
        const int d = idx >> 7, k = idx & 127;
        Wpre0t[idx] = f2bf(Wpre0[k * 128 + d] * INV_C);
        Wpre1t[idx] = f2bf(Wpre1[k * 128 + d] * INV_C);
    }
    if (idx < 32768) {
        const int k = idx >> 7, d = idx & 127;
        Bt0[d * 256 + k] = f2bf(Wp0[idx] * INV_2C);
        Bt1[d * 256 + k] = f2bf(Wp1[idx] * INV_2C);
    }
    if (idx < 4096) {
        if (idx < 2048) {
            const int hh = idx >> 5, k = idx & 31;
            W1t[idx] = (k < 8) ? f2bf(Wm1[k * 64 + hh] * F_INV_SQRT8) : (ushort)0;
        }
        {
            const int c = idx >> 6, k = idx & 63;
            W2t[idx] = f2bf(Wm2[k * 64 + c] * 0.125f);
        }
        if (idx < 1024) {
            const int m = idx >> 6, k = idx & 63;
            W3t[idx] = (m < 4) ? f2bf(Wm3[k * 4 + m] * 0.125f) : (ushort)0;
        }
    }
}

// ---------------------------------------------------------------------------
// Kernel A: fused node pre-transforms via MFMA grouped GEMM (validated r6).
// ---------------------------------------------------------------------------
__global__ __launch_bounds__(512) void node_gemm_kernel(
    const int* __restrict__ prow_map,       // [PROWS]
    const int* __restrict__ tile_spec,      // [PTILES]
    const ushort* __restrict__ As,          // [PROWS][128] bf16
    const ushort* __restrict__ Av0,
    const ushort* __restrict__ Av1,
    const ushort* __restrict__ Av2,
    const ushort* __restrict__ Wsc0t,       // [S][128][128] bf16 (scaled)
    const ushort* __restrict__ Wsc1t,
    const ushort* __restrict__ Wpre0t,      // [128][128] bf16 (scaled)
    const ushort* __restrict__ Wpre1t,
    float* __restrict__ out_sc,             // [N][C][4] (second output)
    ushort4* __restrict__ sv_bf)            // [N][C] bf16x4 workspace
{
    const int l  = threadIdx.x & 63;
    const int w  = threadIdx.x >> 6;
    const int d0 = w * 16;
    const int lr = l & 15;
    const int lg = l >> 4;

    bf16x8 bp0[4], bp1[4];
#pragma unroll
    for (int ks = 0; ks < 4; ++ks) {
        bp0[ks] = *reinterpret_cast<const bf16x8*>(
            Wpre0t + (d0 + lr) * 128 + ks * 32 + lg * 8);
        bp1[ks] = *reinterpret_cast<const bf16x8*>(
            Wpre1t + (d0 + lr) * 128 + ks * 32 + lg * 8);
    }

    const int tile = blockIdx.x;
    const int sp   = tile_spec[tile];
    const int r0   = tile * 16;

    const ushort* as  = As  + (size_t)(r0 + lr) * 128 + lg * 8;
    const ushort* av0 = Av0 + (size_t)(r0 + lr) * 128 + lg * 8;
    const ushort* av1 = Av1 + (size_t)(r0 + lr) * 128 + lg * 8;
    const ushort* av2 = Av2 + (size_t)(r0 + lr) * 128 + lg * 8;
    const ushort* ws0 = Wsc0t + (size_t)sp * 16384 + (d0 + lr) * 128 + lg * 8;
    const ushort* ws1 = Wsc1t + (size_t)sp * 16384 + (d0 + lr) * 128 + lg * 8;

    const f32x4 zero = {0.0f, 0.0f, 0.0f, 0.0f};
    f32x4 aS0 = zero, aS1 = zero, aS2 = zero, aS3 = zero;
    f32x4 aP0 = zero, aP1 = zero, aP2 = zero, aP3 = zero;

#pragma unroll
    for (int ks = 0; ks < 4; ++ks) {
        const bf16x8 a_s  = *reinterpret_cast<const bf16x8*>(as  + ks * 32);
        const bf16x8 a_v0 = *reinterpret_cast<const bf16x8*>(av0 + ks * 32);
        const bf16x8 a_v1 = *reinterpret_cast<const bf16x8*>(av1 + ks * 32);
        const bf16x8 a_v2 = *reinterpret_cast<const bf16x8*>(av2 + ks * 32);
        const bf16x8 bs0  = *reinterpret_cast<const bf16x8*>(ws0 + ks * 32);
        const bf16x8 bs1  = *reinterpret_cast<const bf16x8*>(ws1 + ks * 32);
        aS0 = __builtin_amdgcn_mfma_f32_16x16x32_bf16(a_s,  bs0, aS0, 0, 0, 0);
        aS1 = __builtin_amdgcn_mfma_f32_16x16x32_bf16(a_v0, bs1, aS1, 0, 0, 0);
        aS2 = __builtin_amdgcn_mfma_f32_16x16x32_bf16(a_v1, bs1, aS2, 0, 0, 0);
        aS3 = __builtin_amdgcn_mfma_f32_16x16x32_bf16(a_v2, bs1, aS3, 0, 0, 0);
        aP0 = __builtin_amdgcn_mfma_f32_16x16x32_bf16(a_s,  bp0[ks], aP0, 0, 0, 0);
        aP1 = __builtin_amdgcn_mfma_f32_16x16x32_bf16(a_v0, bp1[ks], aP1, 0, 0, 0);
        aP2 = __builtin_amdgcn_mfma_f32_16x16x32_bf16(a_v1, bp1[ks], aP2, 0, 0, 0);
        aP3 = __builtin_amdgcn_mfma_f32_16x16x32_bf16(a_v2, bp1[ks], aP3, 0, 0, 0);
    }

#pragma unroll
    for (int r = 0; r < 4; ++r) {
        const int row = r0 + lg * 4 + r;
        const int nid = prow_map[row];
        if (nid >= 0) {
            float4 o = {aS0[r], aS1[r], aS2[r], aS3[r]};
            ((float4*)out_sc)[(size_t)nid * C_DIM + (d0 + lr)] = o;
            ushort4 pv = {f2bf(aP0[r]), f2bf(aP1[r]), f2bf(aP2[r]), f2bf(aP3[r])};
            sv_bf[(size_t)nid * C_DIM + (d0 + lr)] = pv;
        }
    }
}

// ---------------------------------------------------------------------------
// Kernel B: edge MLP via MFMA (validated r5). Coef emitted as bf16x8
// (16 B/edge).
// ---------------------------------------------------------------------------
__global__ __launch_bounds__(256) void edge_mlp_mfma_kernel(
    const float* __restrict__ edge_feats,   // [E][8]
    const float* __restrict__ edge_attrs,   // [E][4]
    const ushort* __restrict__ W1t,         // [64][32] bf16 (padded, scaled)
    const ushort* __restrict__ W2t,         // [64][64] bf16 (scaled)
    const ushort* __restrict__ W3t,         // [16][64] bf16 (padded, scaled)
    uint4* __restrict__ coefbf)             // [E] 8x bf16
{
    __shared__ ushort h_lds[4][16][72];

    const int w  = threadIdx.x >> 6;
    const int l  = threadIdx.x & 63;
    const int lr = l & 15;
    const int lg = l >> 4;

    bf16x8 a1[4];
#pragma unroll
    for (int mt = 0; mt < 4; ++mt)
        a1[mt] = *reinterpret_cast<const bf16x8*>(
            W1t + (mt * 16 + lr) * 32 + lg * 8);
    bf16x8 a2[4][2];
#pragma unroll
    for (int mt = 0; mt < 4; ++mt)
#pragma unroll
        for (int ks = 0; ks < 2; ++ks)
            a2[mt][ks] = *reinterpret_cast<const bf16x8*>(
                W2t + (mt * 16 + lr) * 64 + ks * 32 + lg * 8);
    bf16x8 a3[2];
#pragma unroll
    for (int ks = 0; ks < 2; ++ks)
        a3[ks] = *reinterpret_cast<const bf16x8*>(
            W3t + lr * 64 + ks * 32 + lg * 8);

    const int tile = blockIdx.x * 4 + w;
    const int e0   = tile * 16;
    const f32x4 zero = {0.0f, 0.0f, 0.0f, 0.0f};

    bf16x8 b1 = {0, 0, 0, 0, 0, 0, 0, 0};
    if (lg == 0) {
        const float4 q0 = *(const float4*)(edge_feats + (size_t)(e0 + lr) * 8);
        const float4 q1 = *(const float4*)(edge_feats + (size_t)(e0 + lr) * 8 + 4);
        b1[0] = (short)f2bf(q0.x); b1[1] = (short)f2bf(q0.y);
        b1[2] = (short)f2bf(q0.z); b1[3] = (short)f2bf(q0.w);
        b1[4] = (short)f2bf(q1.x); b1[5] = (short)f2bf(q1.y);
        b1[6] = (short)f2bf(q1.z); b1[7] = (short)f2bf(q1.w);
    }

    f32x4 d1[4];
#pragma unroll
    for (int mt = 0; mt < 4; ++mt)
        d1[mt] = __builtin_amdgcn_mfma_f32_16x16x32_bf16(a1[mt], b1, zero, 0, 0, 0);

#pragma unroll
    for (int mt = 0; mt < 4; ++mt) {
        uint2 p;
        p.x = pack2bf(silu(d1[mt][0]), silu(d1[mt][1]));
        p.y = pack2bf(silu(d1[mt][2]), silu(d1[mt][3]));
        *reinterpret_cast<uint2*>(&h_lds[w][lr][mt * 16 + lg * 4]) = p;
    }
    __syncthreads();

    bf16x8 b2[2];
#pragma unroll
    for (int ks = 0; ks < 2; ++ks)
        b2[ks] = *reinterpret_cast<const bf16x8*>(
            &h_lds[w][lr][ks * 32 + lg * 8]);

    f32x4 d2[4];
#pragma unroll
    for (int mt = 0; mt < 4; ++mt) {
        d2[mt] = __builtin_amdgcn_mfma_f32_16x16x32_bf16(a2[mt][0], b2[0], zero, 0, 0, 0);
        d2[mt] = __builtin_amdgcn_mfma_f32_16x16x32_bf16(a2[mt][1], b2[1], d2[mt], 0, 0, 0);
    }

#pragma unroll
    for (int mt = 0; mt < 4; ++mt) {
        uint2 p;
        p.x = pack2bf(silu(d2[mt][0]), silu(d2[mt][1]));
        p.y = pack2bf(silu(d2[mt][2]), silu(d2[mt][3]));
        *reinterpret_cast<uint2*>(&h_lds[w][lr][mt * 16 + lg * 4]) = p;
    }
    __syncthreads();

    bf16x8 b3[2];
#pragma unroll
    for (int ks = 0; ks < 2; ++ks)
        b3[ks] = *reinterpret_cast<const bf16x8*>(
            &h_lds[w][lr][ks * 32 + lg * 8]);

    f32x4 d3;
    d3 = __builtin_amdgcn_mfma_f32_16x16x32_bf16(a3[0], b3[0], zero, 0, 0, 0);
    d3 = __builtin_amdgcn_mfma_f32_16x16x32_bf16(a3[1], b3[1], d3, 0, 0, 0);

    if (lg == 0) {
        const int e = e0 + lr;
        const float4 a = *(const float4*)(edge_attrs + (size_t)e * 4);
        const float mx0 = d3[0], mx1 = d3[1], mx2 = d3[2], mx3 = d3[3];
        uint4 cv;
        cv.x = pack2bf(mx0,                      mx1 * a.y * F_INV_SQRT3);
        cv.y = pack2bf(mx1 * a.z * F_INV_SQRT3,  mx1 * a.w * F_INV_SQRT3);
        cv.z = pack2bf(mx2,                      mx3 * a.y);
        cv.w = pack2bf(mx3 * a.z,                mx3 * a.w);
        coefbf[e] = cv;
    }
}

// ---------------------------------------------------------------------------
// Kernel C1: CSR-gather aggregation — r7 champion structure. A_v now in
// 3-plane layout [comp][N][128] u32 so the fused post GEMM gets contiguous
// 16-node row tiles per component.
// ---------------------------------------------------------------------------
__global__ __launch_bounds__(256) void agg_kernel(
    const int* __restrict__ start,          // [N+1]
    const int* __restrict__ perm,           // [E]
    const int* __restrict__ senders,
    const uint4* __restrict__ coefbf,       // [E] 8x bf16
    const ushort4* __restrict__ sv_bf,      // [N][C] bf16x4
    unsigned int* __restrict__ A_s,         // [N][128] u32 (2x bf16)
    unsigned int* __restrict__ A_v)         // [3][N][128] u32 (2x bf16)
{
    __shared__ int   se_lds[CHUNK];
    __shared__ float sc_lds[CHUNK][8];

    const int n0   = blockIdx.x * 8;
    const int t    = threadIdx.x;
    const int c    = t & 127;
    const int half = t >> 7;

    int nbeg[4], nend[4];
#pragma unroll
    for (int k = 0; k < 4; ++k) {
        nbeg[k] = start[n0 + half * 4 + k];
        nend[k] = start[n0 + half * 4 + k + 1];
    }

    const int blk_beg = start[n0];
    const int blk_end = start[n0 + 8];

    float acc[4][8] = {};

    for (int cb = blk_beg; cb < blk_end; cb += CHUNK) {
        const int cn = min(CHUNK, blk_end - cb);
        __syncthreads();
        for (int j = t; j < cn; j += 256) {
            const int e = perm[cb + j];
            se_lds[j] = senders[e];
            const uint4 cv = coefbf[e];
            float4 lo = {bf2f(cv.x), bf2f_hi(cv.x), bf2f(cv.y), bf2f_hi(cv.y)};
            float4 hi = {bf2f(cv.z), bf2f_hi(cv.z), bf2f(cv.w), bf2f_hi(cv.w)};
            ((float4*)sc_lds[j])[0] = lo;
            ((float4*)sc_lds[j])[1] = hi;
        }
        __syncthreads();

#pragma unroll
        for (int k = 0; k < 4; ++k) {
            const int lo = max(nbeg[k], cb);
            const int hi = min(nend[k], cb + cn);
            int idx = lo;
            for (; idx + 2 <= hi; idx += 2) {
                const int j0 = idx - cb, j1 = j0 + 1;
                const int snd0 = se_lds[j0];
                const int snd1 = se_lds[j1];
                const ushort4 u0 = sv_bf[(size_t)snd0 * C_DIM + c];
                const ushort4 u1 = sv_bf[(size_t)snd1 * C_DIM + c];
                const float* kf0 = sc_lds[j0];
                const float* kf1 = sc_lds[j1];
                const float x0 = bf2f(u0.x), y0 = bf2f(u0.y),
                            z0 = bf2f(u0.z), w0 = bf2f(u0.w);
                const float x1 = bf2f(u1.x), y1 = bf2f(u1.y),
                            z1 = bf2f(u1.z), w1 = bf2f(u1.w);
                acc[k][0] += x0 * kf0[0];
                acc[k][1] += y0 * kf0[1] + z0 * kf0[2] + w0 * kf0[3];
                acc[k][2] += y0 * kf0[4];
                acc[k][3] += z0 * kf0[4];
                acc[k][4] += w0 * kf0[4];
                acc[k][5] += x0 * kf0[5];
                acc[k][6] += x0 * kf0[6];
                acc[k][7] += x0 * kf0[7];
                acc[k][0] += x1 * kf1[0];
                acc[k][1] += y1 * kf1[1] + z1 * kf1[2] + w1 * kf1[3];
                acc[k][2] += y1 * kf1[4];
                acc[k][3] += z1 * kf1[4];
                acc[k][4] += w1 * kf1[4];
                acc[k][5] += x1 * kf1[5];
                acc[k][6] += x1 * kf1[6];
                acc[k][7] += x1 * kf1[7];
            }
            if (idx < hi) {
                const int j = idx - cb;
                const int snd = se_lds[j];
                const ushort4 u = sv_bf[(size_t)snd * C_DIM + c];
                const float* kf = sc_lds[j];
                const float x = bf2f(u.x), y = bf2f(u.y),
                            z = bf2f(u.z), w = bf2f(u.w);
                acc[k][0] += x * kf[0];
                acc[k][1] += y * kf[1] + z * kf[2] + w * kf[3];
                acc[k][2] += y * kf[4];
                acc[k][3] += z * kf[4];
                acc[k][4] += w * kf[4];
                acc[k][5] += x * kf[5];
                acc[k][6] += x * kf[6];
                acc[k][7] += x * kf[7];
            }
        }
    }

#pragma unroll
    for (int k = 0; k < 4; ++k) {
        const int n = n0 + half * 4 + k;
        A_s[(size_t)n * 128 + c] =
            pack2bf(acc[k][0] * F_INV_AVG, acc[k][1] * F_INV_AVG);
        A_v[((size_t)0 * N_NODES + n) * 128 + c] =
            pack2bf(acc[k][2] * F_INV_AVG, acc[k][5] * F_INV_AVG);
        A_v[((size_t)1 * N_NODES + n) * 128 + c] =
            pack2bf(acc[k][3] * F_INV_AVG, acc[k][6] * F_INV_AVG);
        A_v[((size_t)2 * N_NODES + n) * 128 + c] =
            pack2bf(acc[k][4] * F_INV_AVG, acc[k][7] * F_INV_AVG);
    }
}

// ---------------------------------------------------------------------------
// Kernel C2: fused post GEMMs. One block = one 16-node tile; 8 waves = 8
// col tiles. Per wave 4 accumulators (s, v0, v1, v2) sharing cached Bt
// fragments; epilogue writes one coalesced float4 per (node, d).
// ---------------------------------------------------------------------------
__global__ __launch_bounds__(512) void post_gemm_kernel(
    const ushort* __restrict__ A_s,         // [N][256] bf16
    const ushort* __restrict__ A_v,         // [3][N][256] bf16
    const ushort* __restrict__ Bt0,         // [128][256] bf16 (pre-scaled)
    const ushort* __restrict__ Bt1,
    float4* __restrict__ out)               // [N][128] float4
{
    const int l  = threadIdx.x & 63;
    const int w  = threadIdx.x >> 6;
    const int d0 = w * 16;
    const int lr = l & 15;
    const int lg = l >> 4;

    bf16x8 b0frag[8], b1frag[8];
#pragma unroll
    for (int ks = 0; ks < 8; ++ks) {
        b0frag[ks] = *reinterpret_cast<const bf16x8*>(
            Bt0 + (size_t)(d0 + lr) * 256 + ks * 32 + lg * 8);
        b1frag[ks] = *reinterpret_cast<const bf16x8*>(
            Bt1 + (size_t)(d0 + lr) * 256 + ks * 32 + lg * 8);
    }

    const int r0 = blockIdx.x * 16;
    const f32x4 zero = {0.0f, 0.0f, 0.0f, 0.0f};
    f32x4 accS = zero, acc0 = zero, acc1 = zero, acc2 = zero;

    const ushort* aS = A_s + (size_t)(r0 + lr) * 256 + lg * 8;
    const ushort* a0 = A_v + ((size_t)0 * N_NODES + r0 + lr) * 256 + lg * 8;
    const ushort* a1 = A_v + ((size_t)1 * N_NODES + r0 + lr) * 256 + lg * 8;
    const ushort* a2 = A_v + ((size_t)2 * N_NODES + r0 + lr) * 256 + lg * 8;

#pragma unroll
    for (int ks = 0; ks < 8; ++ks) {
        const bf16x8 fS = *reinterpret_cast<const bf16x8*>(aS + ks * 32);
        const bf16x8 f0 = *reinterpret_cast<const bf16x8*>(a0 + ks * 32);
        const bf16x8 f1 = *reinterpret_cast<const bf16x8*>(a1 + ks * 32);
        const bf16x8 f2 = *reinterpret_cast<const bf16x8*>(a2 + ks * 32);
        accS = __builtin_amdgcn_mfma_f32_16x16x32_bf16(fS, b0frag[ks], accS, 0, 0, 0);
        acc0 = __builtin_amdgcn_mfma_f32_16x16x32_bf16(f0, b1frag[ks], acc0, 0, 0, 0);
        acc1 = __builtin_amdgcn_mfma_f32_16x16x32_bf16(f1, b1frag[ks], acc1, 0, 0, 0);
        acc2 = __builtin_amdgcn_mfma_f32_16x16x32_bf16(f2, b1frag[ks], acc2, 0, 0, 0);
    }

#pragma unroll
    for (int r = 0; r < 4; ++r) {
        const int n = r0 + lg * 4 + r;
        float4 o = {accS[r], acc0[r], acc1[r], acc2[r]};
        out[(size_t)n * C_DIM + (d0 + lr)] = o;
    }
}

// ---------------------------------------------------------------------------
extern "C" void kernel_launch(void* const* d_in, const int* in_sizes, int n_in,
                              void* d_out, int out_size, void* d_ws, size_t ws_size,
                              hipStream_t stream)
{
    const int*   specie     = (const int*)d_in[0];
    const float* node_feats = (const float*)d_in[1];
    const float* edge_attrs = (const float*)d_in[2];
    const float* edge_feats = (const float*)d_in[3];
    const int*   senders    = (const int*)d_in[4];
    const int*   receivers  = (const int*)d_in[5];
    const float* Wsc0  = (const float*)d_in[6];
    const float* Wsc1  = (const float*)d_in[7];
    const float* Wpre0 = (const float*)d_in[8];
    const float* Wpre1 = (const float*)d_in[9];
    const float* Wm1   = (const float*)d_in[10];
    const float* Wm2   = (const float*)d_in[11];
    const float* Wm3   = (const float*)d_in[12];
    const float* Wp0   = (const float*)d_in[13];
    const float* Wp1   = (const float*)d_in[14];

    float* out_node = (float*)d_out;                           // [N][C][4]
    float* out_sc   = out_node + (size_t)N_NODES * C_DIM * 4;  // [N][C][4]

    // workspace layout
    char* ws = (char*)d_ws;
    ushort4*      sv_bf = (ushort4*)ws;                               // 16 MB
    unsigned int* A_s   = (unsigned int*)(ws + (size_t)16 * 1024 * 1024);
    unsigned int* A_v   = A_s + (size_t)N_NODES * 128;                // 8+24 MB
    uint4*        coefbf= (uint4*)(A_v + (size_t)3 * N_NODES * 128);  // 4 MB
    ushort*       Asin  = (ushort*)(coefbf + (size_t)E_EDGES);        // 4.2 MB
    ushort*       Av0in = Asin  + (size_t)PROWS * 128;
    ushort*       Av1in = Av0in + (size_t)PROWS * 128;
    ushort*       Av2in = Av1in + (size_t)PROWS * 128;
    ushort*       Bt0   = Av2in + (size_t)PROWS * 128;
    ushort*       Bt1   = Bt0 + 256 * 128;
    ushort*       Wsc0t = Bt1 + 256 * 128;       // [10][128][128]
    ushort*       Wsc1t = Wsc0t + S_SPEC * 128 * 128;
    ushort*       Wpre0t = Wsc1t + S_SPEC * 128 * 128;
    ushort*       Wpre1t = Wpre0t + 128 * 128;
    ushort*       W1t   = Wpre1t + 128 * 128;    // [64][32]
    ushort*       W2t   = W1t + 64 * 32;         // [64][64]
    ushort*       W3t   = W2t + 64 * 64;         // [16][64]
    int* counts    = (int*)(W3t + 16 * 64);
    int* start     = counts + N_NODES;
    int* cursor    = start + (N_NODES + 1);
    int* perm      = cursor + N_NODES;
    int* scnt      = perm + E_EDGES;
    int* poff      = scnt + S_SPEC;
    int* scur      = poff + S_SPEC;
    int* prow_map  = scur + S_SPEC;              // [PROWS]
    int* tile_spec = prow_map + PROWS;           // [PTILES]

    // 1. init (replaces 4 memsets)
    init_kernel<<<(PROWS + 255) / 256, 256, 0, stream>>>(
        counts, scnt, prow_map, tile_spec);

    // 2. histograms (receiver degree + species)
    hist_kernel<<<E_EDGES / 256, 256, 0, stream>>>(
        receivers, counts, specie, scnt);

    // 3. scans (CSR + species padded offsets)
    scan_kernel<<<1, 256, 0, stream>>>(counts, start, cursor, scnt, poff, scur);

    // 4. scatter perm + node placement
    scatter_place_kernel<<<E_EDGES / 256, 256, 0, stream>>>(
        receivers, cursor, perm, specie, poff, scur, prow_map, tile_spec);

    // 5. all conversions
    prep_kernel<<<PROWS * 128 / 256, 256, 0, stream>>>(
        prow_map, node_feats, Asin, Av0in, Av1in, Av2in,
        Wsc0, Wsc1, Wsc0t, Wsc1t, Wpre0, Wpre1, Wpre0t, Wpre1t,
        Wp0, Wp1, Bt0, Bt1, Wm1, Wm2, Wm3, W1t, W2t, W3t);

    // 6. node pre transforms via MFMA (output 2 + sv_bf)
    node_gemm_kernel<<<PTILES, 512, 0, stream>>>(
        prow_map, tile_spec, Asin, Av0in, Av1in, Av2in,
        Wsc0t, Wsc1t, Wpre0t, Wpre1t, out_sc, sv_bf);

    // 7. edge MLP via MFMA -> bf16 coefficients
    edge_mlp_mfma_kernel<<<E_EDGES / 64, 256, 0, stream>>>(
        edge_feats, edge_attrs, W1t, W2t, W3t, coefbf);

    // 8. gather-aggregate (r7 structure, 3-plane A_v) -> bf16 A matrices
    agg_kernel<<<N_NODES / 8, 256, 0, stream>>>(
        start, perm, senders, coefbf, sv_bf, A_s, A_v);

    // 9. fused post GEMM (output 1, coalesced float4 stores)
    post_gemm_kernel<<<N_NODES / 16, 512, 0, stream>>>(
        (const ushort*)A_s, (const ushort*)A_v, Bt0, Bt1, (float4*)out_node);
}

// Round 13
// 219.414 us; speedup vs baseline: 1.0402x; 1.0402x over previous
//
#include <hip/hip_runtime.h>
#include <hip/hip_bf16.h>

// Problem constants
#define N_NODES 16384
#define C_DIM   128
#define E_EDGES 262144
#define S_SPEC  10
#define CHUNK   256
#define PROWS   16544   // N + 10*15 rounded to 16: padded species-sorted rows
#define PTILES  1034    // PROWS / 16

__device__ __constant__ const float INV_C  = 0.08838834764831845f;  // 1/sqrt(128)
__device__ __constant__ const float INV_2C = 0.0625f;               // 1/sqrt(256)
#define F_INV_SQRT3 0.5773502691896258f
#define F_INV_SQRT8 0.35355339059327373f
#define F_INV_AVG   0.0625f   // 1/16 neighbors

typedef __attribute__((ext_vector_type(8))) short bf16x8;
typedef __attribute__((ext_vector_type(4))) float f32x4;

__device__ __forceinline__ float silu(float x) {
    return x / (1.0f + __expf(-x));
}

__device__ __forceinline__ unsigned short f2bf(float x) {
    __hip_bfloat16 h = __float2bfloat16(x);
    return *reinterpret_cast<unsigned short*>(&h);
}

__device__ __forceinline__ unsigned int pack2bf(float lo, float hi) {
    return (unsigned int)f2bf(lo) | ((unsigned int)f2bf(hi) << 16);
}

__device__ __forceinline__ float bf2f(unsigned int u16) {
    return __uint_as_float((u16 & 0xffffu) << 16);
}

__device__ __forceinline__ float bf2f_hi(unsigned int u) {
    return __uint_as_float(u & 0xffff0000u);
}

// ---------------------------------------------------------------------------
// Init: replaces 4 memsets with one dispatch.
// ---------------------------------------------------------------------------
__global__ __launch_bounds__(256) void init_kernel(
    int* __restrict__ counts, int* __restrict__ scnt,
    int* __restrict__ prow_map, int* __restrict__ tile_spec)
{
    const int idx = blockIdx.x * 256 + threadIdx.x;
    if (idx < N_NODES) counts[idx] = 0;
    if (idx < S_SPEC)  scnt[idx] = 0;
    if (idx < PROWS)   prow_map[idx] = -1;
    if (idx < PTILES)  tile_spec[idx] = 0;
}

// ---------------------------------------------------------------------------
// Histograms: receiver degree (all blocks) + species (first 64 blocks).
// ---------------------------------------------------------------------------
__global__ __launch_bounds__(256) void hist_kernel(
    const int* __restrict__ receivers, int* __restrict__ cnt,
    const int* __restrict__ specie, int* __restrict__ scnt)
{
    __shared__ int h[S_SPEC];
    const int t = threadIdx.x;
    const bool doSpec = blockIdx.x < (N_NODES / 256);
    if (doSpec) {
        if (t < S_SPEC) h[t] = 0;
        __syncthreads();
        atomicAdd(&h[specie[blockIdx.x * 256 + t]], 1);
    }
    const int e = blockIdx.x * 256 + t;
    atomicAdd(&cnt[receivers[e]], 1);
    if (doSpec) {
        __syncthreads();
        if (t < S_SPEC) atomicAdd(&scnt[t], h[t]);
    }
}

// ---------------------------------------------------------------------------
// Scans: 16K-node CSR scan (+cursor copy) and 10-species padded scan.
// ---------------------------------------------------------------------------
__global__ __launch_bounds__(256) void scan_kernel(
    const int* __restrict__ cnt, int* __restrict__ start,
    int* __restrict__ cursor,
    const int* __restrict__ scnt, int* __restrict__ poff,
    int* __restrict__ scur)
{
    __shared__ int sums[256];
    const int t = threadIdx.x;
    if (t == 0) {
        int pa = 0;
        for (int i = 0; i < S_SPEC; ++i) {
            poff[i] = pa;
            scur[i] = 0;
            pa += ((scnt[i] + 15) >> 4) << 4;
        }
    }
    int s = 0;
    for (int i = 0; i < 64; ++i) s += cnt[t * 64 + i];
    sums[t] = s;
    __syncthreads();
    if (t == 0) {
        int a = 0;
        for (int i = 0; i < 256; ++i) { int v = sums[i]; sums[i] = a; a += v; }
    }
    __syncthreads();
    int a = sums[t];
    for (int i = 0; i < 64; ++i) {
        int v = cnt[t * 64 + i];
        start[t * 64 + i] = a;
        cursor[t * 64 + i] = a;
        a += v;
    }
    if (t == 255) start[N_NODES] = a;
}

// ---------------------------------------------------------------------------
// Scatter: CSR edge permutation (all blocks) + node placement (first 64).
// ---------------------------------------------------------------------------
__global__ __launch_bounds__(256) void scatter_place_kernel(
    const int* __restrict__ receivers, int* __restrict__ cursor,
    int* __restrict__ perm,
    const int* __restrict__ specie, const int* __restrict__ poff,
    int* __restrict__ scur,
    int* __restrict__ prow_map, int* __restrict__ tile_spec)
{
    const int t = threadIdx.x;
    const int e = blockIdx.x * 256 + t;
    const int pos = atomicAdd(&cursor[receivers[e]], 1);
    perm[pos] = e;

    if (blockIdx.x < (N_NODES / 256)) {
        __shared__ int h[S_SPEC];
        __shared__ int bbase[S_SPEC];
        if (t < S_SPEC) h[t] = 0;
        __syncthreads();
        const int n = blockIdx.x * 256 + t;
        const int s = specie[n];
        const int lrank = atomicAdd(&h[s], 1);
        __syncthreads();
        if (t < S_SPEC && h[t] > 0) bbase[t] = atomicAdd(&scur[t], h[t]);
        __syncthreads();
        const int p = poff[s] + bbase[s] + lrank;
        prow_map[p] = n;
        tile_spec[p >> 4] = s;    // benign race: same value within a tile
    }
}

// ---------------------------------------------------------------------------
// Prep: all bf16 conversions in one dispatch (streaming, range-switched).
// ---------------------------------------------------------------------------
__global__ __launch_bounds__(256) void prep_kernel(
    const int* __restrict__ prow_map, const float* __restrict__ node_feats,
    ushort* __restrict__ As, ushort* __restrict__ Av0,
    ushort* __restrict__ Av1, ushort* __restrict__ Av2,
    const float* __restrict__ Wsc0, const float* __restrict__ Wsc1,
    ushort* __restrict__ Wsc0t, ushort* __restrict__ Wsc1t,
    const float* __restrict__ Wpre0, const float* __restrict__ Wpre1,
    ushort* __restrict__ Wpre0t, ushort* __restrict__ Wpre1t,
    const float* __restrict__ Wp0, const float* __restrict__ Wp1,
    ushort* __restrict__ Bt0, ushort* __restrict__ Bt1,
    const float* __restrict__ Wm1, const float* __restrict__ Wm2,
    const float* __restrict__ Wm3,
    ushort* __restrict__ W1t, ushort* __restrict__ W2t,
    ushort* __restrict__ W3t)
{
    const int idx = blockIdx.x * 256 + threadIdx.x;   // 0 .. PROWS*128-1
    {
        const int p = idx >> 7, c = idx & 127;
        const int nid = prow_map[p];
        float4 f = {0.0f, 0.0f, 0.0f, 0.0f};
        if (nid >= 0) f = ((const float4*)node_feats)[nid * C_DIM + c];
        As [idx] = f2bf(f.x);
        Av0[idx] = f2bf(f.y);
        Av1[idx] = f2bf(f.z);
        Av2[idx] = f2bf(f.w);
    }
    if (idx < S_SPEC * 128 * 128) {
        const int s = idx >> 14, d = (idx >> 7) & 127, k = idx & 127;
        Wsc0t[idx] = f2bf(Wsc0[s * 16384 + k * 128 + d] * INV_C);
        Wsc1t[idx] = f2bf(Wsc1[s * 16384 + k * 128 + d] * INV_C);
    }
    if (idx < 16384) {
        const int d = idx >> 7, k = idx & 127;
        Wpre0t[idx] = f2bf(Wpre0[k * 128 + d] * INV_C);
        Wpre1t[idx] = f2bf(Wpre1[k * 128 + d] * INV_C);
    }
    if (idx < 32768) {
        const int k = idx >> 7, d = idx & 127;
        Bt0[d * 256 + k] = f2bf(Wp0[idx] * INV_2C);
        Bt1[d * 256 + k] = f2bf(Wp1[idx] * INV_2C);
    }
    if (idx < 4096) {
        if (idx < 2048) {
            const int hh = idx >> 5, k = idx & 31;
            W1t[idx] = (k < 8) ? f2bf(Wm1[k * 64 + hh] * F_INV_SQRT8) : (ushort)0;
        }
        {
            const int c = idx >> 6, k = idx & 63;
            W2t[idx] = f2bf(Wm2[k * 64 + c] * 0.125f);
        }
        if (idx < 1024) {
            const int m = idx >> 6, k = idx & 63;
            W3t[idx] = (m < 4) ? f2bf(Wm3[k * 4 + m] * 0.125f) : (ushort)0;
        }
    }
}

// ---------------------------------------------------------------------------
// Kernel A: fused node pre-transforms via MFMA grouped GEMM (validated r6).
// ---------------------------------------------------------------------------
__global__ __launch_bounds__(512) void node_gemm_kernel(
    const int* __restrict__ prow_map,       // [PROWS]
    const int* __restrict__ tile_spec,      // [PTILES]
    const ushort* __restrict__ As,          // [PROWS][128] bf16
    const ushort* __restrict__ Av0,
    const ushort* __restrict__ Av1,
    const ushort* __restrict__ Av2,
    const ushort* __restrict__ Wsc0t,       // [S][128][128] bf16 (scaled)
    const ushort* __restrict__ Wsc1t,
    const ushort* __restrict__ Wpre0t,      // [128][128] bf16 (scaled)
    const ushort* __restrict__ Wpre1t,
    float* __restrict__ out_sc,             // [N][C][4] (second output)
    ushort4* __restrict__ sv_bf)            // [N][C] bf16x4 workspace
{
    const int l  = threadIdx.x & 63;
    const int w  = threadIdx.x >> 6;
    const int d0 = w * 16;
    const int lr = l & 15;
    const int lg = l >> 4;

    bf16x8 bp0[4], bp1[4];
#pragma unroll
    for (int ks = 0; ks < 4; ++ks) {
        bp0[ks] = *reinterpret_cast<const bf16x8*>(
            Wpre0t + (d0 + lr) * 128 + ks * 32 + lg * 8);
        bp1[ks] = *reinterpret_cast<const bf16x8*>(
            Wpre1t + (d0 + lr) * 128 + ks * 32 + lg * 8);
    }

    const int tile = blockIdx.x;
    const int sp   = tile_spec[tile];
    const int r0   = tile * 16;

    const ushort* as  = As  + (size_t)(r0 + lr) * 128 + lg * 8;
    const ushort* av0 = Av0 + (size_t)(r0 + lr) * 128 + lg * 8;
    const ushort* av1 = Av1 + (size_t)(r0 + lr) * 128 + lg * 8;
    const ushort* av2 = Av2 + (size_t)(r0 + lr) * 128 + lg * 8;
    const ushort* ws0 = Wsc0t + (size_t)sp * 16384 + (d0 + lr) * 128 + lg * 8;
    const ushort* ws1 = Wsc1t + (size_t)sp * 16384 + (d0 + lr) * 128 + lg * 8;

    const f32x4 zero = {0.0f, 0.0f, 0.0f, 0.0f};
    f32x4 aS0 = zero, aS1 = zero, aS2 = zero, aS3 = zero;
    f32x4 aP0 = zero, aP1 = zero, aP2 = zero, aP3 = zero;

#pragma unroll
    for (int ks = 0; ks < 4; ++ks) {
        const bf16x8 a_s  = *reinterpret_cast<const bf16x8*>(as  + ks * 32);
        const bf16x8 a_v0 = *reinterpret_cast<const bf16x8*>(av0 + ks * 32);
        const bf16x8 a_v1 = *reinterpret_cast<const bf16x8*>(av1 + ks * 32);
        const bf16x8 a_v2 = *reinterpret_cast<const bf16x8*>(av2 + ks * 32);
        const bf16x8 bs0  = *reinterpret_cast<const bf16x8*>(ws0 + ks * 32);
        const bf16x8 bs1  = *reinterpret_cast<const bf16x8*>(ws1 + ks * 32);
        aS0 = __builtin_amdgcn_mfma_f32_16x16x32_bf16(a_s,  bs0, aS0, 0, 0, 0);
        aS1 = __builtin_amdgcn_mfma_f32_16x16x32_bf16(a_v0, bs1, aS1, 0, 0, 0);
        aS2 = __builtin_amdgcn_mfma_f32_16x16x32_bf16(a_v1, bs1, aS2, 0, 0, 0);
        aS3 = __builtin_amdgcn_mfma_f32_16x16x32_bf16(a_v2, bs1, aS3, 0, 0, 0);
        aP0 = __builtin_amdgcn_mfma_f32_16x16x32_bf16(a_s,  bp0[ks], aP0, 0, 0, 0);
        aP1 = __builtin_amdgcn_mfma_f32_16x16x32_bf16(a_v0, bp1[ks], aP1, 0, 0, 0);
        aP2 = __builtin_amdgcn_mfma_f32_16x16x32_bf16(a_v1, bp1[ks], aP2, 0, 0, 0);
        aP3 = __builtin_amdgcn_mfma_f32_16x16x32_bf16(a_v2, bp1[ks], aP3, 0, 0, 0);
    }

#pragma unroll
    for (int r = 0; r < 4; ++r) {
        const int row = r0 + lg * 4 + r;
        const int nid = prow_map[row];
        if (nid >= 0) {
            float4 o = {aS0[r], aS1[r], aS2[r], aS3[r]};
            ((float4*)out_sc)[(size_t)nid * C_DIM + (d0 + lr)] = o;
            ushort4 pv = {f2bf(aP0[r]), f2bf(aP1[r]), f2bf(aP2[r]), f2bf(aP3[r])};
            sv_bf[(size_t)nid * C_DIM + (d0 + lr)] = pv;
        }
    }
}

// ---------------------------------------------------------------------------
// Kernel B: edge MLP via MFMA (validated r5). Coef emitted as bf16x8.
// ---------------------------------------------------------------------------
__global__ __launch_bounds__(256) void edge_mlp_mfma_kernel(
    const float* __restrict__ edge_feats,   // [E][8]
    const float* __restrict__ edge_attrs,   // [E][4]
    const ushort* __restrict__ W1t,         // [64][32] bf16 (padded, scaled)
    const ushort* __restrict__ W2t,         // [64][64] bf16 (scaled)
    const ushort* __restrict__ W3t,         // [16][64] bf16 (padded, scaled)
    uint4* __restrict__ coefbf)             // [E] 8x bf16
{
    __shared__ ushort h_lds[4][16][72];

    const int w  = threadIdx.x >> 6;
    const int l  = threadIdx.x & 63;
    const int lr = l & 15;
    const int lg = l >> 4;

    bf16x8 a1[4];
#pragma unroll
    for (int mt = 0; mt < 4; ++mt)
        a1[mt] = *reinterpret_cast<const bf16x8*>(
            W1t + (mt * 16 + lr) * 32 + lg * 8);
    bf16x8 a2[4][2];
#pragma unroll
    for (int mt = 0; mt < 4; ++mt)
#pragma unroll
        for (int ks = 0; ks < 2; ++ks)
            a2[mt][ks] = *reinterpret_cast<const bf16x8*>(
                W2t + (mt * 16 + lr) * 64 + ks * 32 + lg * 8);
    bf16x8 a3[2];
#pragma unroll
    for (int ks = 0; ks < 2; ++ks)
        a3[ks] = *reinterpret_cast<const bf16x8*>(
            W3t + lr * 64 + ks * 32 + lg * 8);

    const int tile = blockIdx.x * 4 + w;
    const int e0   = tile * 16;
    const f32x4 zero = {0.0f, 0.0f, 0.0f, 0.0f};

    bf16x8 b1 = {0, 0, 0, 0, 0, 0, 0, 0};
    if (lg == 0) {
        const float4 q0 = *(const float4*)(edge_feats + (size_t)(e0 + lr) * 8);
        const float4 q1 = *(const float4*)(edge_feats + (size_t)(e0 + lr) * 8 + 4);
        b1[0] = (short)f2bf(q0.x); b1[1] = (short)f2bf(q0.y);
        b1[2] = (short)f2bf(q0.z); b1[3] = (short)f2bf(q0.w);
        b1[4] = (short)f2bf(q1.x); b1[5] = (short)f2bf(q1.y);
        b1[6] = (short)f2bf(q1.z); b1[7] = (short)f2bf(q1.w);
    }

    f32x4 d1[4];
#pragma unroll
    for (int mt = 0; mt < 4; ++mt)
        d1[mt] = __builtin_amdgcn_mfma_f32_16x16x32_bf16(a1[mt], b1, zero, 0, 0, 0);

#pragma unroll
    for (int mt = 0; mt < 4; ++mt) {
        uint2 p;
        p.x = pack2bf(silu(d1[mt][0]), silu(d1[mt][1]));
        p.y = pack2bf(silu(d1[mt][2]), silu(d1[mt][3]));
        *reinterpret_cast<uint2*>(&h_lds[w][lr][mt * 16 + lg * 4]) = p;
    }
    __syncthreads();

    bf16x8 b2[2];
#pragma unroll
    for (int ks = 0; ks < 2; ++ks)
        b2[ks] = *reinterpret_cast<const bf16x8*>(
            &h_lds[w][lr][ks * 32 + lg * 8]);

    f32x4 d2[4];
#pragma unroll
    for (int mt = 0; mt < 4; ++mt) {
        d2[mt] = __builtin_amdgcn_mfma_f32_16x16x32_bf16(a2[mt][0], b2[0], zero, 0, 0, 0);
        d2[mt] = __builtin_amdgcn_mfma_f32_16x16x32_bf16(a2[mt][1], b2[1], d2[mt], 0, 0, 0);
    }

#pragma unroll
    for (int mt = 0; mt < 4; ++mt) {
        uint2 p;
        p.x = pack2bf(silu(d2[mt][0]), silu(d2[mt][1]));
        p.y = pack2bf(silu(d2[mt][2]), silu(d2[mt][3]));
        *reinterpret_cast<uint2*>(&h_lds[w][lr][mt * 16 + lg * 4]) = p;
    }
    __syncthreads();

    bf16x8 b3[2];
#pragma unroll
    for (int ks = 0; ks < 2; ++ks)
        b3[ks] = *reinterpret_cast<const bf16x8*>(
            &h_lds[w][lr][ks * 32 + lg * 8]);

    f32x4 d3;
    d3 = __builtin_amdgcn_mfma_f32_16x16x32_bf16(a3[0], b3[0], zero, 0, 0, 0);
    d3 = __builtin_amdgcn_mfma_f32_16x16x32_bf16(a3[1], b3[1], d3, 0, 0, 0);

    if (lg == 0) {
        const int e = e0 + lr;
        const float4 a = *(const float4*)(edge_attrs + (size_t)e * 4);
        const float mx0 = d3[0], mx1 = d3[1], mx2 = d3[2], mx3 = d3[3];
        uint4 cv;
        cv.x = pack2bf(mx0,                      mx1 * a.y * F_INV_SQRT3);
        cv.y = pack2bf(mx1 * a.z * F_INV_SQRT3,  mx1 * a.w * F_INV_SQRT3);
        cv.z = pack2bf(mx2,                      mx3 * a.y);
        cv.w = pack2bf(mx3 * a.z,                mx3 * a.w);
        coefbf[e] = cv;
    }
}

// ---------------------------------------------------------------------------
// Kernel C: fused gather-aggregate + post GEMM.
// Main loop: r7 champion gather (8 nodes/block, CHUNK-staged edge scalars).
// Epilogue: pack acc -> bf16 plane tile in LDS [16][264] (rows 0-7 valid;
// rows 8-15 uninitialized -> only affect discarded D rows), then 4 waves x
// 2 col-tiles x 4 planes x 8 ks MFMAs vs Bt0/Bt1; lanes lg<2 write one
// coalesced float4 per (node, d). Removes post dispatch + 64 MB A traffic.
// ---------------------------------------------------------------------------
__global__ __launch_bounds__(256) void agg_kernel(
    const int* __restrict__ start,          // [N+1]
    const int* __restrict__ perm,           // [E]
    const int* __restrict__ senders,
    const uint4* __restrict__ coefbf,       // [E] 8x bf16
    const ushort4* __restrict__ sv_bf,      // [N][C] bf16x4
    const ushort* __restrict__ Bt0,         // [128][256] bf16 (pre-scaled)
    const ushort* __restrict__ Bt1,
    float4* __restrict__ out)               // [N][128] float4 (first output)
{
    __shared__ int    se_lds[CHUNK];
    __shared__ float  sc_lds[CHUNK][8];
    __shared__ ushort a_lds[16][264];       // plane tile, padded stride

    const int n0   = blockIdx.x * 8;
    const int t    = threadIdx.x;
    const int c    = t & 127;
    const int half = t >> 7;

    int nbeg[4], nend[4];
#pragma unroll
    for (int k = 0; k < 4; ++k) {
        nbeg[k] = start[n0 + half * 4 + k];
        nend[k] = start[n0 + half * 4 + k + 1];
    }

    const int blk_beg = start[n0];
    const int blk_end = start[n0 + 8];

    float acc[4][8] = {};

    for (int cb = blk_beg; cb < blk_end; cb += CHUNK) {
        const int cn = min(CHUNK, blk_end - cb);
        __syncthreads();
        for (int j = t; j < cn; j += 256) {
            const int e = perm[cb + j];
            se_lds[j] = senders[e];
            const uint4 cv = coefbf[e];
            float4 lo = {bf2f(cv.x), bf2f_hi(cv.x), bf2f(cv.y), bf2f_hi(cv.y)};
            float4 hi = {bf2f(cv.z), bf2f_hi(cv.z), bf2f(cv.w), bf2f_hi(cv.w)};
            ((float4*)sc_lds[j])[0] = lo;
            ((float4*)sc_lds[j])[1] = hi;
        }
        __syncthreads();

#pragma unroll
        for (int k = 0; k < 4; ++k) {
            const int lo = max(nbeg[k], cb);
            const int hi = min(nend[k], cb + cn);
            int idx = lo;
            for (; idx + 2 <= hi; idx += 2) {
                const int j0 = idx - cb, j1 = j0 + 1;
                const int snd0 = se_lds[j0];
                const int snd1 = se_lds[j1];
                const ushort4 u0 = sv_bf[(size_t)snd0 * C_DIM + c];
                const ushort4 u1 = sv_bf[(size_t)snd1 * C_DIM + c];
                const float* kf0 = sc_lds[j0];
                const float* kf1 = sc_lds[j1];
                const float x0 = bf2f(u0.x), y0 = bf2f(u0.y),
                            z0 = bf2f(u0.z), w0 = bf2f(u0.w);
                const float x1 = bf2f(u1.x), y1 = bf2f(u1.y),
                            z1 = bf2f(u1.z), w1 = bf2f(u1.w);
                acc[k][0] += x0 * kf0[0];
                acc[k][1] += y0 * kf0[1] + z0 * kf0[2] + w0 * kf0[3];
                acc[k][2] += y0 * kf0[4];
                acc[k][3] += z0 * kf0[4];
                acc[k][4] += w0 * kf0[4];
                acc[k][5] += x0 * kf0[5];
                acc[k][6] += x0 * kf0[6];
                acc[k][7] += x0 * kf0[7];
                acc[k][0] += x1 * kf1[0];
                acc[k][1] += y1 * kf1[1] + z1 * kf1[2] + w1 * kf1[3];
                acc[k][2] += y1 * kf1[4];
                acc[k][3] += z1 * kf1[4];
                acc[k][4] += w1 * kf1[4];
                acc[k][5] += x1 * kf1[5];
                acc[k][6] += x1 * kf1[6];
                acc[k][7] += x1 * kf1[7];
            }
            if (idx < hi) {
                const int j = idx - cb;
                const int snd = se_lds[j];
                const ushort4 u = sv_bf[(size_t)snd * C_DIM + c];
                const float* kf = sc_lds[j];
                const float x = bf2f(u.x), y = bf2f(u.y),
                            z = bf2f(u.z), w = bf2f(u.w);
                acc[k][0] += x * kf[0];
                acc[k][1] += y * kf[1] + z * kf[2] + w * kf[3];
                acc[k][2] += y * kf[4];
                acc[k][3] += z * kf[4];
                acc[k][4] += w * kf[4];
                acc[k][5] += x * kf[5];
                acc[k][6] += x * kf[6];
                acc[k][7] += x * kf[7];
            }
        }
    }

    // ---- pack per-plane bf16 pairs: A[n][k=c*2+m] for 4 planes ----
    unsigned int pv[4][4];
#pragma unroll
    for (int k = 0; k < 4; ++k) {
        pv[0][k] = pack2bf(acc[k][0] * F_INV_AVG, acc[k][1] * F_INV_AVG);
        pv[1][k] = pack2bf(acc[k][2] * F_INV_AVG, acc[k][5] * F_INV_AVG);
        pv[2][k] = pack2bf(acc[k][3] * F_INV_AVG, acc[k][6] * F_INV_AVG);
        pv[3][k] = pack2bf(acc[k][4] * F_INV_AVG, acc[k][7] * F_INV_AVG);
    }

    // ---- fused post GEMM epilogue ----
    const int l  = t & 63;
    const int wv = t >> 6;          // 4 waves: wave wv owns cols [wv*32, wv*32+32)
    const int d0 = wv * 32;
    const int lr = l & 15;
    const int lg = l >> 4;

    // cache Bt1 fragments (reused for 3 vector planes)
    bf16x8 bt1f[2][8];
#pragma unroll
    for (int tt = 0; tt < 2; ++tt)
#pragma unroll
        for (int ks = 0; ks < 8; ++ks)
            bt1f[tt][ks] = *reinterpret_cast<const bf16x8*>(
                Bt1 + (size_t)(d0 + tt * 16 + lr) * 256 + ks * 32 + lg * 8);

    const f32x4 zero = {0.0f, 0.0f, 0.0f, 0.0f};
    f32x4 pS[2] = {zero, zero}, p0[2] = {zero, zero};
    f32x4 p1[2] = {zero, zero}, p2[2] = {zero, zero};

#pragma unroll
    for (int p = 0; p < 4; ++p) {
        __syncthreads();
#pragma unroll
        for (int k = 0; k < 4; ++k)
            *reinterpret_cast<unsigned int*>(&a_lds[half * 4 + k][c * 2]) =
                pv[p][k];
        __syncthreads();
#pragma unroll
        for (int ks = 0; ks < 8; ++ks) {
            const bf16x8 af = *reinterpret_cast<const bf16x8*>(
                &a_lds[lr][ks * 32 + lg * 8]);
#pragma unroll
            for (int tt = 0; tt < 2; ++tt) {
                bf16x8 bf;
                if (p == 0)
                    bf = *reinterpret_cast<const bf16x8*>(
                        Bt0 + (size_t)(d0 + tt * 16 + lr) * 256 + ks * 32 + lg * 8);
                else
                    bf = bt1f[tt][ks];
                if (p == 0)
                    pS[tt] = __builtin_amdgcn_mfma_f32_16x16x32_bf16(af, bf, pS[tt], 0, 0, 0);
                else if (p == 1)
                    p0[tt] = __builtin_amdgcn_mfma_f32_16x16x32_bf16(af, bf, p0[tt], 0, 0, 0);
                else if (p == 2)
                    p1[tt] = __builtin_amdgcn_mfma_f32_16x16x32_bf16(af, bf, p1[tt], 0, 0, 0);
                else
                    p2[tt] = __builtin_amdgcn_mfma_f32_16x16x32_bf16(af, bf, p2[tt], 0, 0, 0);
            }
        }
    }

    // store: D rows 0-7 valid (lg<2); col = d0 + tt*16 + lr
    if (lg < 2) {
#pragma unroll
        for (int tt = 0; tt < 2; ++tt)
#pragma unroll
            for (int r = 0; r < 4; ++r) {
                const int n = n0 + lg * 4 + r;
                float4 o = {pS[tt][r], p0[tt][r], p1[tt][r], p2[tt][r]};
                out[(size_t)n * C_DIM + d0 + tt * 16 + lr] = o;
            }
    }
}

// ---------------------------------------------------------------------------
extern "C" void kernel_launch(void* const* d_in, const int* in_sizes, int n_in,
                              void* d_out, int out_size, void* d_ws, size_t ws_size,
                              hipStream_t stream)
{
    const int*   specie     = (const int*)d_in[0];
    const float* node_feats = (const float*)d_in[1];
    const float* edge_attrs = (const float*)d_in[2];
    const float* edge_feats = (const float*)d_in[3];
    const int*   senders    = (const int*)d_in[4];
    const int*   receivers  = (const int*)d_in[5];
    const float* Wsc0  = (const float*)d_in[6];
    const float* Wsc1  = (const float*)d_in[7];
    const float* Wpre0 = (const float*)d_in[8];
    const float* Wpre1 = (const float*)d_in[9];
    const float* Wm1   = (const float*)d_in[10];
    const float* Wm2   = (const float*)d_in[11];
    const float* Wm3   = (const float*)d_in[12];
    const float* Wp0   = (const float*)d_in[13];
    const float* Wp1   = (const float*)d_in[14];

    float* out_node = (float*)d_out;                           // [N][C][4]
    float* out_sc   = out_node + (size_t)N_NODES * C_DIM * 4;  // [N][C][4]

    // workspace layout (A_s/A_v removed — post fused into agg)
    char* ws = (char*)d_ws;
    ushort4*      sv_bf  = (ushort4*)ws;                              // 16 MB
    uint4*        coefbf = (uint4*)(ws + (size_t)16 * 1024 * 1024);   // 4 MB
    ushort*       Asin  = (ushort*)(coefbf + (size_t)E_EDGES);        // 4.2 MB
    ushort*       Av0in = Asin  + (size_t)PROWS * 128;
    ushort*       Av1in = Av0in + (size_t)PROWS * 128;
    ushort*       Av2in = Av1in + (size_t)PROWS * 128;
    ushort*       Bt0   = Av2in + (size_t)PROWS * 128;
    ushort*       Bt1   = Bt0 + 256 * 128;
    ushort*       Wsc0t = Bt1 + 256 * 128;       // [10][128][128]
    ushort*       Wsc1t = Wsc0t + S_SPEC * 128 * 128;
    ushort*       Wpre0t = Wsc1t + S_SPEC * 128 * 128;
    ushort*       Wpre1t = Wpre0t + 128 * 128;
    ushort*       W1t   = Wpre1t + 128 * 128;    // [64][32]
    ushort*       W2t   = W1t + 64 * 32;         // [64][64]
    ushort*       W3t   = W2t + 64 * 64;         // [16][64]
    int* counts    = (int*)(W3t + 16 * 64);
    int* start     = counts + N_NODES;
    int* cursor    = start + (N_NODES + 1);
    int* perm      = cursor + N_NODES;
    int* scnt      = perm + E_EDGES;
    int* poff      = scnt + S_SPEC;
    int* scur      = poff + S_SPEC;
    int* prow_map  = scur + S_SPEC;              // [PROWS]
    int* tile_spec = prow_map + PROWS;           // [PTILES]

    // 1. init (replaces 4 memsets)
    init_kernel<<<(PROWS + 255) / 256, 256, 0, stream>>>(
        counts, scnt, prow_map, tile_spec);

    // 2. histograms (receiver degree + species)
    hist_kernel<<<E_EDGES / 256, 256, 0, stream>>>(
        receivers, counts, specie, scnt);

    // 3. scans (CSR + species padded offsets)
    scan_kernel<<<1, 256, 0, stream>>>(counts, start, cursor, scnt, poff, scur);

    // 4. scatter perm + node placement
    scatter_place_kernel<<<E_EDGES / 256, 256, 0, stream>>>(
        receivers, cursor, perm, specie, poff, scur, prow_map, tile_spec);

    // 5. all conversions
    prep_kernel<<<PROWS * 128 / 256, 256, 0, stream>>>(
        prow_map, node_feats, Asin, Av0in, Av1in, Av2in,
        Wsc0, Wsc1, Wsc0t, Wsc1t, Wpre0, Wpre1, Wpre0t, Wpre1t,
        Wp0, Wp1, Bt0, Bt1, Wm1, Wm2, Wm3, W1t, W2t, W3t);

    // 6. node pre transforms via MFMA (output 2 + sv_bf)
    node_gemm_kernel<<<PTILES, 512, 0, stream>>>(
        prow_map, tile_spec, Asin, Av0in, Av1in, Av2in,
        Wsc0t, Wsc1t, Wpre0t, Wpre1t, out_sc, sv_bf);

    // 7. edge MLP via MFMA -> bf16 coefficients
    edge_mlp_mfma_kernel<<<E_EDGES / 64, 256, 0, stream>>>(
        edge_feats, edge_attrs, W1t, W2t, W3t, coefbf);

    // 8. fused gather-aggregate + post GEMM (output 1)
    agg_kernel<<<N_NODES / 8, 256, 0, stream>>>(
        start, perm, senders, coefbf, sv_bf, Bt0, Bt1, (float4*)out_node);
}